// Round 1
// baseline (1492.332 us; speedup 1.0000x reference)
//
#include <hip/hip_runtime.h>
#include <cstdint>
#include <cstddef>

// Problem constants (match reference setup_inputs)
constexpr int N_  = 20000;
constexpr int E_  = 320000;
constexpr int DIM_ = 128;
constexpr int L_  = 4;

__device__ __forceinline__ float gelu_f(float x) {
  // JAX default gelu: approximate=True (tanh form)
  float x3 = x * x * x;
  float t = tanhf(0.7978845608028654f * (x + 0.044715f * x3));
  return 0.5f * x * (1.0f + t);
}

// ---------------------------------------------------------------------------
// GEMM: C[M,Nc] = A[M,K] @ B[K,Nc] + bias  (EPI=1: gelu, EPI=2: +res)
// BM=64, BN=128, BK=16, 128 threads, 8x8 per-thread tile.
// LDS layout uses segment offsets (seg s -> s*8 + (s>>2)*4) so that the
// per-kk ds_read_b128s are conflict-free (A) / 2-way (B) per m136 rules.
// ---------------------------------------------------------------------------
template <int EPI>
__global__ __launch_bounds__(128) void gemm_k(
    const float* __restrict__ A, const float* __restrict__ B,
    const float* __restrict__ bias, const float* __restrict__ res,
    float* __restrict__ C, int M, int Nc, int K)
{
  __shared__ float As[16][72];    // phys row = r + ((r>>5)<<2), max 67
  __shared__ float Bs[16][140];   // phys col = c + ((c>>5)<<2), max 139
  const int tid = threadIdx.x;
  const int tx = tid & 15, ty = tid >> 4;
  const int bm = blockIdx.x * 64, bn = blockIdx.y * 128;

  float acc[8][8];
#pragma unroll
  for (int i = 0; i < 8; ++i)
#pragma unroll
    for (int j = 0; j < 8; ++j) acc[i][j] = 0.f;

  const int pa = ty * 8 + ((ty >> 2) << 2);
  const int pb = tx * 8 + ((tx >> 2) << 2);

  for (int k0 = 0; k0 < K; k0 += 16) {
    // A tile: 64 rows x 16 k, 2 float4 per thread, transposed store
#pragma unroll
    for (int i = 0; i < 2; ++i) {
      int l = tid + i * 128;
      int row = l >> 2, kq = (l & 3) << 2;
      float4 av = make_float4(0.f, 0.f, 0.f, 0.f);
      int gr = bm + row;
      if (gr < M) av = *(const float4*)(A + (size_t)gr * K + k0 + kq);
      int pr = row + ((row >> 5) << 2);
      As[kq + 0][pr] = av.x; As[kq + 1][pr] = av.y;
      As[kq + 2][pr] = av.z; As[kq + 3][pr] = av.w;
    }
    // B tile: 16 k x 128 cols, 4 float4 per thread
#pragma unroll
    for (int i = 0; i < 4; ++i) {
      int l = tid + i * 128;
      int kr = l >> 5, c4 = (l & 31) << 2;
      float4 bvv = *(const float4*)(B + (size_t)(k0 + kr) * Nc + bn + c4);
      int pc = c4 + ((c4 >> 5) << 2);
      *(float4*)&Bs[kr][pc] = bvv;
    }
    __syncthreads();
#pragma unroll
    for (int kk = 0; kk < 16; ++kk) {
      float4 a0 = *(float4*)&As[kk][pa];
      float4 a1 = *(float4*)&As[kk][pa + 4];
      float4 b0 = *(float4*)&Bs[kk][pb];
      float4 b1 = *(float4*)&Bs[kk][pb + 4];
      float a[8] = {a0.x, a0.y, a0.z, a0.w, a1.x, a1.y, a1.z, a1.w};
      float b[8] = {b0.x, b0.y, b0.z, b0.w, b1.x, b1.y, b1.z, b1.w};
#pragma unroll
      for (int i2 = 0; i2 < 8; ++i2)
#pragma unroll
        for (int j2 = 0; j2 < 8; ++j2)
          acc[i2][j2] = fmaf(a[i2], b[j2], acc[i2][j2]);
    }
    __syncthreads();
  }

#pragma unroll
  for (int i = 0; i < 8; ++i) {
    int gr = bm + ty * 8 + i;
    if (gr >= M) break;
#pragma unroll
    for (int jq = 0; jq < 2; ++jq) {
      int gc = bn + tx * 8 + jq * 4;
      float4 bb = *(const float4*)(bias + gc);
      float4 o;
      o.x = acc[i][jq * 4 + 0] + bb.x;
      o.y = acc[i][jq * 4 + 1] + bb.y;
      o.z = acc[i][jq * 4 + 2] + bb.z;
      o.w = acc[i][jq * 4 + 3] + bb.w;
      if (EPI == 1) { o.x = gelu_f(o.x); o.y = gelu_f(o.y); o.z = gelu_f(o.z); o.w = gelu_f(o.w); }
      if (EPI == 2) {
        float4 rr = *(const float4*)(res + (size_t)gr * Nc + gc);
        o.x += rr.x; o.y += rr.y; o.z += rr.z; o.w += rr.w;
      }
      *(float4*)(C + (size_t)gr * Nc + gc) = o;
    }
  }
}

// ---------------------------------------------------------------------------
// CSR build
// ---------------------------------------------------------------------------
__global__ __launch_bounds__(256) void init_zero_k(int* deg, int* cur, float* gsum, int n) {
  int i = blockIdx.x * blockDim.x + threadIdx.x;
  int st = gridDim.x * blockDim.x;
  for (int j = i; j < n; j += st) { deg[j] = 0; cur[j] = 0; }
  if (i < 128) gsum[i] = 0.f;
}

__global__ __launch_bounds__(256) void deg_k(const int* __restrict__ dst, int* __restrict__ deg, int E) {
  int e = blockIdx.x * blockDim.x + threadIdx.x;
  if (e < E) atomicAdd(&deg[dst[e]], 1);
}

__global__ __launch_bounds__(1024) void scan_k(const int* __restrict__ deg, int* __restrict__ offs, int n) {
  __shared__ int part[1024];
  int tid = threadIdx.x;
  const int chunk = (n + 1023) / 1024;
  int base = tid * chunk;
  int s = 0;
  for (int j = 0; j < chunk; ++j) { int idx = base + j; if (idx < n) s += deg[idx]; }
  part[tid] = s;
  __syncthreads();
  int own = s;
  for (int off = 1; off < 1024; off <<= 1) {
    int t = (tid >= off) ? part[tid - off] : 0;
    __syncthreads();
    part[tid] += t;
    __syncthreads();
  }
  int run = part[tid] - own;  // exclusive prefix
  for (int j = 0; j < chunk; ++j) {
    int idx = base + j;
    if (idx <= n) offs[idx] = run;
    if (idx < n) run += deg[idx];
  }
}

__global__ __launch_bounds__(256) void fill_k(
    const int* __restrict__ src, const int* __restrict__ dst,
    const int* __restrict__ offs, int* __restrict__ cur,
    int* __restrict__ csrc, int E)
{
  int e = blockIdx.x * blockDim.x + threadIdx.x;
  if (e < E) {
    int d = dst[e];
    int p = atomicAdd(&cur[d], 1);
    csrc[offs[d] + p] = src[e];
  }
}

// ---------------------------------------------------------------------------
// Fused attention: per (node, head-pair) wave, online softmax over CSR edges.
// agg may alias q (each wave reads only its own q row before writing it).
// ---------------------------------------------------------------------------
__global__ __launch_bounds__(256) void attn_k(
    const float* __restrict__ q, const float* __restrict__ k, const float* __restrict__ v,
    const int* __restrict__ offs, const int* __restrict__ csrc,
    float* __restrict__ agg, int M)
{
  int gw = (int)((blockIdx.x * blockDim.x + threadIdx.x) >> 6);
  int lane = threadIdx.x & 63;
  int n = gw >> 1, hp = gw & 1;
  if (n >= M) return;
  int col = hp * 64 + lane;  // == head*32 + d for the two heads this wave owns
  float qv = q[(size_t)n * 128 + col] * 0.17677669529663687f;  // 1/sqrt(32)
  float m = -3.0e38f, den = 0.f, acc = 0.f;
  int e0 = offs[n], e1 = offs[n + 1];
  for (int e = e0; e < e1; ++e) {
    int s = csrc[e];
    float kv = k[(size_t)s * 128 + col];
    float p = qv * kv;
    p += __shfl_xor(p, 1);
    p += __shfl_xor(p, 2);
    p += __shfl_xor(p, 4);
    p += __shfl_xor(p, 8);
    p += __shfl_xor(p, 16);   // dot over the 32-lane half-wave (one head)
    float vv = v[(size_t)s * 128 + col];
    float nm = fmaxf(m, p);
    float c = __expf(m - nm);
    float w = __expf(p - nm);
    den = den * c + w;
    acc = acc * c + w * vv;
    m = nm;
  }
  agg[(size_t)n * 128 + col] = (e1 > e0) ? (acc / den) : 0.f;
}

// ---------------------------------------------------------------------------
// LayerNorm(x + res) per row, one 64-lane wave per row (2 elems/lane)
// ---------------------------------------------------------------------------
__global__ __launch_bounds__(256) void ln_res_k(
    const float* __restrict__ x, const float* __restrict__ res,
    const float* __restrict__ w, const float* __restrict__ b,
    float* __restrict__ out, int M)
{
  int row = (int)((blockIdx.x * blockDim.x + threadIdx.x) >> 6);
  int lane = threadIdx.x & 63;
  if (row >= M) return;
  const float* xr = x + (size_t)row * 128;
  const float* rr = res + (size_t)row * 128;
  float v0 = xr[lane] + rr[lane];
  float v1 = xr[lane + 64] + rr[lane + 64];
  float s = v0 + v1;
#pragma unroll
  for (int d = 1; d < 64; d <<= 1) s += __shfl_xor(s, d);
  float mean = s * (1.f / 128.f);
  float e0 = v0 - mean, e1 = v1 - mean;
  float qs = e0 * e0 + e1 * e1;
#pragma unroll
  for (int d = 1; d < 64; d <<= 1) qs += __shfl_xor(qs, d);
  float rstd = rsqrtf(qs * (1.f / 128.f) + 1e-5f);
  out[(size_t)row * 128 + lane]      = e0 * rstd * w[lane] + b[lane];
  out[(size_t)row * 128 + lane + 64] = e1 * rstd * w[lane + 64] + b[lane + 64];
}

// ---------------------------------------------------------------------------
// Column sum of h (for mean pool), partial per block + atomic
// ---------------------------------------------------------------------------
__global__ __launch_bounds__(256) void colsum_k(const float* __restrict__ h, float* __restrict__ gsum, int M) {
  __shared__ float sd[256];
  int tid = threadIdx.x;
  int d = tid & 127, half = tid >> 7;
  float s = 0.f;
  for (int r = blockIdx.x * 2 + half; r < M; r += gridDim.x * 2)
    s += h[(size_t)r * 128 + d];
  sd[tid] = s;
  __syncthreads();
  if (tid < 128) atomicAdd(&gsum[d], sd[tid] + sd[tid + 128]);
}

__global__ __launch_bounds__(256) void copy_k(const float* __restrict__ s, float* __restrict__ d, int n) {
  int i = blockIdx.x * blockDim.x + threadIdx.x;
  int st = gridDim.x * blockDim.x;
  for (; i < n; i += st) d[i] = s[i];
}

// ---------------------------------------------------------------------------
// Classifier head: g -> LN -> MLP(128,256)->gelu->128 -> logits(10). 1 block.
// ---------------------------------------------------------------------------
__global__ __launch_bounds__(256) void classifier_k(
    const float* __restrict__ gsum,
    const float* __restrict__ lnw, const float* __restrict__ lnb,
    const float* __restrict__ cw1, const float* __restrict__ cb1,
    const float* __restrict__ cw2, const float* __restrict__ cb2,
    const float* __restrict__ clsw, const float* __restrict__ clsb,
    float* __restrict__ out_logits, float* __restrict__ out_g, float invN)
{
  __shared__ float z[128], h1[256], z2[128];
  int tid = threadIdx.x;
  if (tid < 128) {
    float gg = gsum[tid] * invN;
    out_g[tid] = gg;
    z[tid] = gg;
  }
  __syncthreads();
  if (tid < 64) {
    float a = z[tid], b2 = z[tid + 64];
    float s = a + b2;
#pragma unroll
    for (int d = 1; d < 64; d <<= 1) s += __shfl_xor(s, d);
    float mean = s * (1.f / 128.f);
    float ea = a - mean, eb = b2 - mean;
    float sq = ea * ea + eb * eb;
#pragma unroll
    for (int d = 1; d < 64; d <<= 1) sq += __shfl_xor(sq, d);
    float rstd = rsqrtf(sq * (1.f / 128.f) + 1e-5f);
    z[tid]      = ea * rstd * lnw[tid] + lnb[tid];
    z[tid + 64] = eb * rstd * lnw[tid + 64] + lnb[tid + 64];
  }
  __syncthreads();
  {
    float acc = cb1[tid];
    for (int f = 0; f < 128; ++f) acc = fmaf(z[f], cw1[f * 256 + tid], acc);
    h1[tid] = gelu_f(acc);
  }
  __syncthreads();
  if (tid < 128) {
    float acc = cb2[tid];
    for (int f = 0; f < 256; ++f) acc = fmaf(h1[f], cw2[f * 128 + tid], acc);
    z2[tid] = acc;
  }
  __syncthreads();
  if (tid < 10) {
    float acc = clsb[tid];
    for (int f = 0; f < 128; ++f) acc = fmaf(z2[f], clsw[f * 10 + tid], acc);
    out_logits[tid] = acc;
  }
}

// ---------------------------------------------------------------------------
extern "C" void kernel_launch(void* const* d_in, const int* in_sizes, int n_in,
                              void* d_out, int out_size, void* d_ws, size_t ws_size,
                              hipStream_t stream) {
  const float* node_features = (const float*)d_in[0];
  const int*   ei            = (const int*)d_in[1];
  // d_in[2] edge_features: unused (edge_emb computed but unused in reference)
  const float* emb_w = (const float*)d_in[3];
  const float* emb_b = (const float*)d_in[4];
  const float* qw  = (const float*)d_in[7];  const float* qb  = (const float*)d_in[8];
  const float* kw  = (const float*)d_in[9];  const float* kb  = (const float*)d_in[10];
  const float* vw  = (const float*)d_in[11]; const float* vb  = (const float*)d_in[12];
  const float* ow  = (const float*)d_in[13]; const float* ob  = (const float*)d_in[14];
  const float* lnw = (const float*)d_in[15]; const float* lnb = (const float*)d_in[16];
  const float* mw1 = (const float*)d_in[17]; const float* mb1 = (const float*)d_in[18];
  const float* mw2 = (const float*)d_in[19]; const float* mb2 = (const float*)d_in[20];
  const float* clnw = (const float*)d_in[21]; const float* clnb = (const float*)d_in[22];
  const float* cw1 = (const float*)d_in[23]; const float* cb1 = (const float*)d_in[24];
  const float* cw2 = (const float*)d_in[25]; const float* cb2 = (const float*)d_in[26];
  const float* clsw = (const float*)d_in[27]; const float* clsb = (const float*)d_in[28];

  float* out = (float*)d_out;                    // [logits(10) | h(N*128) | g(128)]
  float* out_h = out + 10;
  float* out_g = out + 10 + (size_t)N_ * DIM_;

  // Workspace layout (floats then ints), ~84 MB
  float* h   = (float*)d_ws;
  float* bq  = h   + (size_t)N_ * DIM_;
  float* bk  = bq  + (size_t)N_ * DIM_;
  float* bv  = bk  + (size_t)N_ * DIM_;
  float* hid = bv  + (size_t)N_ * DIM_;          // N x 512
  float* gsum = hid + (size_t)N_ * 512;          // 128
  int* deg  = (int*)(gsum + 128);
  int* cur  = deg + N_;
  int* offs = cur + N_;                          // N+1
  int* csrc = offs + N_ + 1;                     // E

  const int* esrc = ei;
  const int* edst = ei + E_;

  const dim3 gemmBlk(128);
  const int MB = (N_ + 63) / 64;                 // 313

  // CSR build (reused across all 4 layers)
  init_zero_k<<<64, 256, 0, stream>>>(deg, cur, gsum, N_);
  deg_k<<<(E_ + 255) / 256, 256, 0, stream>>>(edst, deg, E_);
  scan_k<<<1, 1024, 0, stream>>>(deg, offs, N_);
  fill_k<<<(E_ + 255) / 256, 256, 0, stream>>>(esrc, edst, offs, cur, csrc, E_);

  // Node embedding: h = nf @ emb_w + emb_b
  gemm_k<0><<<dim3(MB, 1), gemmBlk, 0, stream>>>(node_features, emb_w, emb_b, nullptr, h, N_, 128, 64);

  for (int i = 0; i < L_; ++i) {
    const float* qwi = qw + (size_t)i * DIM_ * DIM_;
    const float* kwi = kw + (size_t)i * DIM_ * DIM_;
    const float* vwi = vw + (size_t)i * DIM_ * DIM_;
    const float* owi = ow + (size_t)i * DIM_ * DIM_;
    const float* mw1i = mw1 + (size_t)i * DIM_ * 512;
    const float* mw2i = mw2 + (size_t)i * 512 * DIM_;

    gemm_k<0><<<dim3(MB, 1), gemmBlk, 0, stream>>>(h, qwi, qb + i * DIM_, nullptr, bq, N_, 128, 128);
    gemm_k<0><<<dim3(MB, 1), gemmBlk, 0, stream>>>(h, kwi, kb + i * DIM_, nullptr, bk, N_, 128, 128);
    gemm_k<0><<<dim3(MB, 1), gemmBlk, 0, stream>>>(h, vwi, vb + i * DIM_, nullptr, bv, N_, 128, 128);

    // attention: 2 waves per node (4 heads), agg aliases bq
    attn_k<<<(2 * N_ * 64 + 255) / 256, 256, 0, stream>>>(bq, bk, bv, offs, csrc, bq, N_);

    // O-projection into bk
    gemm_k<0><<<dim3(MB, 1), gemmBlk, 0, stream>>>(bq, owi, ob + i * DIM_, nullptr, bk, N_, 128, 128);

    // ln_out (bv) = LN(bk + h)
    ln_res_k<<<(N_ * 64 + 255) / 256, 256, 0, stream>>>(bk, h, lnw + i * DIM_, lnb + i * DIM_, bv, N_);

    // MLP: hid = gelu(bv @ mw1 + mb1); h = hid @ mw2 + mb2 + bv
    gemm_k<1><<<dim3(MB, 4), gemmBlk, 0, stream>>>(bv, mw1i, mb1 + i * 512, nullptr, hid, N_, 512, 128);
    gemm_k<2><<<dim3(MB, 1), gemmBlk, 0, stream>>>(hid, mw2i, mb2 + i * DIM_, bv, h, N_, 128, 512);
  }

  copy_k<<<2048, 256, 0, stream>>>(h, out_h, N_ * DIM_);
  colsum_k<<<64, 256, 0, stream>>>(h, gsum, N_);
  classifier_k<<<1, 256, 0, stream>>>(gsum, clnw, clnb, cw1, cb1, cw2, cb2, clsw, clsb,
                                      out, out_g, 1.0f / (float)N_);
}

// Round 2
// 1301.634 us; speedup vs baseline: 1.1465x; 1.1465x over previous
//
#include <hip/hip_runtime.h>
#include <hip/hip_bf16.h>
#include <cstdint>
#include <cstddef>

constexpr int N_  = 20000;
constexpr int E_  = 320000;
constexpr int DIM_ = 128;
constexpr int L_  = 4;
constexpr int MP_ = 20032;   // M padded to multiple of 64 (tile tail reads stay in-bounds)

typedef short bf16x8 __attribute__((ext_vector_type(8)));
typedef float f32x4  __attribute__((ext_vector_type(4)));

__device__ __forceinline__ float gelu_f(float x) {
  float x3 = x * x * x;
  float t = tanhf(0.7978845608028654f * (x + 0.044715f * x3));
  return 0.5f * x * (1.0f + t);
}

__device__ __forceinline__ unsigned short f2bf(float x) {  // round-to-nearest-even
  unsigned u = __float_as_uint(x);
  u += 0x7fff + ((u >> 16) & 1);
  return (unsigned short)(u >> 16);
}
__device__ __forceinline__ float bf2f(unsigned short s) {
  return __uint_as_float((unsigned)s << 16);
}
__device__ __forceinline__ void splitf(float x, unsigned short& h, unsigned short& l) {
  h = f2bf(x);
  l = f2bf(x - bf2f(h));
}

// ---------------------------------------------------------------------------
// MFMA GEMM, bf16x2 split (Ahi*Bhi + Ahi*Blo + Alo*Bhi ~= fp32 precision).
// Block: 256 thr = 4 waves; BM=64 (16 rows/wave); BN=128 per blockIdx.y chunk.
// A planes [M][K] bf16 row-major; Bt planes [Nc][K] bf16 (pre-transposed).
// 16x16x32 fragments: A/B lane: row|col = lane&15, k0 = (lane>>4)*8 (contig 8).
// C/D: col = lane&15, row = (lane>>4)*4 + reg.
// EPI: 0 none, 1 gelu, 2 +res. WF32: write fp32 C. WBF: write hi/lo planes.
// ---------------------------------------------------------------------------
template <int EPI, bool WF32, bool WBF>
__global__ __launch_bounds__(256) void mgemm_k(
    const unsigned short* __restrict__ Ahi, const unsigned short* __restrict__ Alo,
    const unsigned short* __restrict__ Bthi, const unsigned short* __restrict__ Btlo,
    const float* __restrict__ bias, const float* __restrict__ res,
    float* __restrict__ Cf, unsigned short* __restrict__ Chi, unsigned short* __restrict__ Clo,
    int M, int Nc, int K)
{
  const int wave = threadIdx.x >> 6;
  const int lane = threadIdx.x & 63;
  const int l15  = lane & 15;
  const int kq8  = (lane >> 4) * 8;
  const int r0   = blockIdx.x * 64 + wave * 16;
  const int c0   = blockIdx.y * 128;

  f32x4 acc[8];
#pragma unroll
  for (int ct = 0; ct < 8; ++ct) acc[ct] = (f32x4){0.f, 0.f, 0.f, 0.f};

  const unsigned short* arh = Ahi + (size_t)(r0 + l15) * K + kq8;
  const unsigned short* arl = Alo + (size_t)(r0 + l15) * K + kq8;
  const unsigned short* bth = Bthi + (size_t)(c0 + l15) * K + kq8;
  const unsigned short* btl = Btlo + (size_t)(c0 + l15) * K + kq8;

  for (int k0 = 0; k0 < K; k0 += 32) {
    bf16x8 ah = *(const bf16x8*)(arh + k0);
    bf16x8 al = *(const bf16x8*)(arl + k0);
#pragma unroll
    for (int ct = 0; ct < 8; ++ct) {
      const size_t boff = (size_t)ct * 16 * K + k0;
      bf16x8 bh = *(const bf16x8*)(bth + boff);
      bf16x8 bl = *(const bf16x8*)(btl + boff);
      acc[ct] = __builtin_amdgcn_mfma_f32_16x16x32_bf16(ah, bh, acc[ct], 0, 0, 0);
      acc[ct] = __builtin_amdgcn_mfma_f32_16x16x32_bf16(ah, bl, acc[ct], 0, 0, 0);
      acc[ct] = __builtin_amdgcn_mfma_f32_16x16x32_bf16(al, bh, acc[ct], 0, 0, 0);
    }
  }

  const int ccol  = lane & 15;
  const int crow0 = (lane >> 4) * 4;
#pragma unroll
  for (int ct = 0; ct < 8; ++ct) {
    int gc = c0 + ct * 16 + ccol;
    float bb = bias[gc];
#pragma unroll
    for (int r = 0; r < 4; ++r) {
      int gr = r0 + crow0 + r;
      if (gr >= M) continue;
      float o = acc[ct][r] + bb;
      if (EPI == 1) o = gelu_f(o);
      if (EPI == 2) o += res[(size_t)gr * Nc + gc];
      if (WF32) Cf[(size_t)gr * Nc + gc] = o;
      if (WBF) {
        unsigned short hh, ll;
        splitf(o, hh, ll);
        Chi[(size_t)gr * Nc + gc] = hh;
        Clo[(size_t)gr * Nc + gc] = ll;
      }
    }
  }
}

// ---------------------------------------------------------------------------
// Weight transpose + bf16 split: in = Lm matrices of [K][Nc] fp32;
// out planes at  l*layerStride + (rowOff + c)*K + k   (i.e. [c][k] transposed)
// ---------------------------------------------------------------------------
__global__ __launch_bounds__(256) void wsplit_k(
    const float* __restrict__ in, unsigned short* __restrict__ hi,
    unsigned short* __restrict__ lo, int Lm, int K, int Nc,
    int layerStride, int rowOff)
{
  int total = Lm * K * Nc;
  for (int idx = blockIdx.x * blockDim.x + threadIdx.x; idx < total;
       idx += gridDim.x * blockDim.x) {
    int l = idx / (K * Nc);
    int r = idx - l * (K * Nc);
    int k = r / Nc;
    int c = r - k * Nc;
    float x = in[idx];
    size_t op = (size_t)l * layerStride + (size_t)(rowOff + c) * K + k;
    unsigned short hh, ll;
    splitf(x, hh, ll);
    hi[op] = hh; lo[op] = ll;
  }
}

// combined qkv bias: [L][384] from qb,kb,vb [L][128]
__global__ __launch_bounds__(256) void qkvbias_k(
    const float* __restrict__ qb, const float* __restrict__ kb,
    const float* __restrict__ vb, float* __restrict__ out)
{
  int idx = blockIdx.x * blockDim.x + threadIdx.x;
  if (idx >= L_ * 384) return;
  int l = idx / 384, c = idx - l * 384;
  float x = (c < 128) ? qb[l * 128 + c] : (c < 256) ? kb[l * 128 + c - 128] : vb[l * 128 + c - 256];
  out[idx] = x;
}

// split node_features fp32 -> hi/lo planes (no transpose)
__global__ __launch_bounds__(256) void nfsplit_k(
    const float* __restrict__ in, unsigned short* __restrict__ hi,
    unsigned short* __restrict__ lo, int total)
{
  for (int i = blockIdx.x * blockDim.x + threadIdx.x; i < total; i += gridDim.x * blockDim.x) {
    unsigned short hh, ll;
    splitf(in[i], hh, ll);
    hi[i] = hh; lo[i] = ll;
  }
}

// ---------------------------------------------------------------------------
// CSR build
// ---------------------------------------------------------------------------
__global__ __launch_bounds__(256) void init_zero_k(int* deg, int* cur, float* gsum, int n) {
  int i = blockIdx.x * blockDim.x + threadIdx.x;
  int st = gridDim.x * blockDim.x;
  for (int j = i; j < n; j += st) { deg[j] = 0; cur[j] = 0; }
  if (i < 128) gsum[i] = 0.f;
}

__global__ __launch_bounds__(256) void deg_k(const int* __restrict__ dst, int* __restrict__ deg, int E) {
  int e = blockIdx.x * blockDim.x + threadIdx.x;
  if (e < E) atomicAdd(&deg[dst[e]], 1);
}

__global__ __launch_bounds__(1024) void scan_k(const int* __restrict__ deg, int* __restrict__ offs, int n) {
  __shared__ int part[1024];
  int tid = threadIdx.x;
  const int chunk = (n + 1023) / 1024;
  int base = tid * chunk;
  int s = 0;
  for (int j = 0; j < chunk; ++j) { int idx = base + j; if (idx < n) s += deg[idx]; }
  part[tid] = s;
  __syncthreads();
  int own = s;
  for (int off = 1; off < 1024; off <<= 1) {
    int t = (tid >= off) ? part[tid - off] : 0;
    __syncthreads();
    part[tid] += t;
    __syncthreads();
  }
  int run = part[tid] - own;
  for (int j = 0; j < chunk; ++j) {
    int idx = base + j;
    if (idx <= n) offs[idx] = run;
    if (idx < n) run += deg[idx];
  }
}

__global__ __launch_bounds__(256) void fill_k(
    const int* __restrict__ src, const int* __restrict__ dst,
    const int* __restrict__ offs, int* __restrict__ cur,
    int* __restrict__ csrc, int E)
{
  int e = blockIdx.x * blockDim.x + threadIdx.x;
  if (e < E) {
    int d = dst[e];
    int p = atomicAdd(&cur[d], 1);
    csrc[offs[d] + p] = src[e];
  }
}

// ---------------------------------------------------------------------------
// Fused attention over CSR, online softmax. qkv fused buffer [M][384]:
// q at col, k at 128+col, v at 256+col. Output: agg hi/lo bf16 planes [M][128].
// One wave per (node, head-pair): 32-lane half-wave = one head.
// ---------------------------------------------------------------------------
__global__ __launch_bounds__(256) void attn_k(
    const float* __restrict__ qkv,
    const int* __restrict__ offs, const int* __restrict__ csrc,
    unsigned short* __restrict__ aggHi, unsigned short* __restrict__ aggLo, int M)
{
  int gw = (int)((blockIdx.x * blockDim.x + threadIdx.x) >> 6);
  int lane = threadIdx.x & 63;
  int n = gw >> 1, hp = gw & 1;
  if (n >= M) return;
  int col = hp * 64 + lane;
  float qv = qkv[(size_t)n * 384 + col] * 0.17677669529663687f;  // 1/sqrt(32)
  float m = -3.0e38f, den = 0.f, acc = 0.f;
  int e0 = offs[n], e1 = offs[n + 1];
  for (int e = e0; e < e1; ++e) {
    int s = csrc[e];
    const float* krow = qkv + (size_t)s * 384;
    float kv = krow[128 + col];
    float p = qv * kv;
    p += __shfl_xor(p, 1);
    p += __shfl_xor(p, 2);
    p += __shfl_xor(p, 4);
    p += __shfl_xor(p, 8);
    p += __shfl_xor(p, 16);
    float vv = krow[256 + col];
    float nm = fmaxf(m, p);
    float c = __expf(m - nm);
    float w = __expf(p - nm);
    den = den * c + w;
    acc = acc * c + w * vv;
    m = nm;
  }
  float o = (e1 > e0) ? (acc / den) : 0.f;
  unsigned short hh, ll;
  splitf(o, hh, ll);
  aggHi[(size_t)n * 128 + col] = hh;
  aggLo[(size_t)n * 128 + col] = ll;
}

// ---------------------------------------------------------------------------
// LayerNorm(x + res): fp32 out (may alias x) + hi/lo planes
// ---------------------------------------------------------------------------
__global__ __launch_bounds__(256) void ln_res_k(
    const float* x, const float* __restrict__ res,
    const float* __restrict__ w, const float* __restrict__ b,
    float* outF, unsigned short* __restrict__ outHi, unsigned short* __restrict__ outLo, int M)
{
  int row = (int)((blockIdx.x * blockDim.x + threadIdx.x) >> 6);
  int lane = threadIdx.x & 63;
  if (row >= M) return;
  const float* xr = x + (size_t)row * 128;
  const float* rr = res + (size_t)row * 128;
  float v0 = xr[lane] + rr[lane];
  float v1 = xr[lane + 64] + rr[lane + 64];
  float s = v0 + v1;
#pragma unroll
  for (int d = 1; d < 64; d <<= 1) s += __shfl_xor(s, d);
  float mean = s * (1.f / 128.f);
  float e0 = v0 - mean, e1 = v1 - mean;
  float qs = e0 * e0 + e1 * e1;
#pragma unroll
  for (int d = 1; d < 64; d <<= 1) qs += __shfl_xor(qs, d);
  float rstd = rsqrtf(qs * (1.f / 128.f) + 1e-5f);
  float o0 = e0 * rstd * w[lane] + b[lane];
  float o1 = e1 * rstd * w[lane + 64] + b[lane + 64];
  outF[(size_t)row * 128 + lane] = o0;
  outF[(size_t)row * 128 + lane + 64] = o1;
  unsigned short hh, ll;
  splitf(o0, hh, ll);
  outHi[(size_t)row * 128 + lane] = hh; outLo[(size_t)row * 128 + lane] = ll;
  splitf(o1, hh, ll);
  outHi[(size_t)row * 128 + lane + 64] = hh; outLo[(size_t)row * 128 + lane + 64] = ll;
}

// ---------------------------------------------------------------------------
__global__ __launch_bounds__(256) void colsum_k(const float* __restrict__ h, float* __restrict__ gsum, int M) {
  __shared__ float sd[256];
  int tid = threadIdx.x;
  int d = tid & 127, half = tid >> 7;
  float s = 0.f;
  for (int r = blockIdx.x * 2 + half; r < M; r += gridDim.x * 2)
    s += h[(size_t)r * 128 + d];
  sd[tid] = s;
  __syncthreads();
  if (tid < 128) atomicAdd(&gsum[d], sd[tid] + sd[tid + 128]);
}

__global__ __launch_bounds__(256) void copy_k(const float* __restrict__ s, float* __restrict__ d, int n) {
  int i = blockIdx.x * blockDim.x + threadIdx.x;
  int st = gridDim.x * blockDim.x;
  for (; i < n; i += st) d[i] = s[i];
}

__global__ __launch_bounds__(256) void classifier_k(
    const float* __restrict__ gsum,
    const float* __restrict__ lnw, const float* __restrict__ lnb,
    const float* __restrict__ cw1, const float* __restrict__ cb1,
    const float* __restrict__ cw2, const float* __restrict__ cb2,
    const float* __restrict__ clsw, const float* __restrict__ clsb,
    float* __restrict__ out_logits, float* __restrict__ out_g, float invN)
{
  __shared__ float z[128], h1[256], z2[128];
  int tid = threadIdx.x;
  if (tid < 128) {
    float gg = gsum[tid] * invN;
    out_g[tid] = gg;
    z[tid] = gg;
  }
  __syncthreads();
  if (tid < 64) {
    float a = z[tid], b2 = z[tid + 64];
    float s = a + b2;
#pragma unroll
    for (int d = 1; d < 64; d <<= 1) s += __shfl_xor(s, d);
    float mean = s * (1.f / 128.f);
    float ea = a - mean, eb = b2 - mean;
    float sq = ea * ea + eb * eb;
#pragma unroll
    for (int d = 1; d < 64; d <<= 1) sq += __shfl_xor(sq, d);
    float rstd = rsqrtf(sq * (1.f / 128.f) + 1e-5f);
    z[tid]      = ea * rstd * lnw[tid] + lnb[tid];
    z[tid + 64] = eb * rstd * lnw[tid + 64] + lnb[tid + 64];
  }
  __syncthreads();
  {
    float acc = cb1[tid];
    for (int f = 0; f < 128; ++f) acc = fmaf(z[f], cw1[f * 256 + tid], acc);
    h1[tid] = gelu_f(acc);
  }
  __syncthreads();
  if (tid < 128) {
    float acc = cb2[tid];
    for (int f = 0; f < 256; ++f) acc = fmaf(h1[f], cw2[f * 128 + tid], acc);
    z2[tid] = acc;
  }
  __syncthreads();
  if (tid < 10) {
    float acc = clsb[tid];
    for (int f = 0; f < 128; ++f) acc = fmaf(z2[f], clsw[f * 10 + tid], acc);
    out_logits[tid] = acc;
  }
}

// ---------------------------------------------------------------------------
extern "C" void kernel_launch(void* const* d_in, const int* in_sizes, int n_in,
                              void* d_out, int out_size, void* d_ws, size_t ws_size,
                              hipStream_t stream) {
  const float* node_features = (const float*)d_in[0];
  const int*   ei            = (const int*)d_in[1];
  const float* emb_w = (const float*)d_in[3];
  const float* emb_b = (const float*)d_in[4];
  const float* qw  = (const float*)d_in[7];  const float* qb  = (const float*)d_in[8];
  const float* kw  = (const float*)d_in[9];  const float* kb  = (const float*)d_in[10];
  const float* vw  = (const float*)d_in[11]; const float* vb  = (const float*)d_in[12];
  const float* ow  = (const float*)d_in[13]; const float* ob  = (const float*)d_in[14];
  const float* lnw = (const float*)d_in[15]; const float* lnb = (const float*)d_in[16];
  const float* mw1 = (const float*)d_in[17]; const float* mb1 = (const float*)d_in[18];
  const float* mw2 = (const float*)d_in[19]; const float* mb2 = (const float*)d_in[20];
  const float* clnw = (const float*)d_in[21]; const float* clnb = (const float*)d_in[22];
  const float* cw1 = (const float*)d_in[23]; const float* cb1 = (const float*)d_in[24];
  const float* cw2 = (const float*)d_in[25]; const float* cb2 = (const float*)d_in[26];
  const float* clsw = (const float*)d_in[27]; const float* clsb = (const float*)d_in[28];

  float* out = (float*)d_out;
  float* out_h = out + 10;
  float* out_g = out + 10 + (size_t)N_ * DIM_;

  // ---- workspace bump allocator (256B aligned chunks) ----
  char* p = (char*)d_ws;
  auto alloc = [&](size_t bytes) { char* r = p; p += (bytes + 255) & ~(size_t)255; return r; };

  float* h    = (float*)alloc((size_t)MP_ * 128 * 4);
  float* qkv  = (float*)alloc((size_t)MP_ * 384 * 4);
  float* tmp  = (float*)alloc((size_t)MP_ * 128 * 4);   // O out, then LN f32 (in-place)
  unsigned short* h_hi = (unsigned short*)alloc((size_t)MP_ * 128 * 2);
  unsigned short* h_lo = (unsigned short*)alloc((size_t)MP_ * 128 * 2);
  unsigned short* sp_hi = (unsigned short*)alloc((size_t)MP_ * 128 * 2);  // agg planes, then LN planes
  unsigned short* sp_lo = (unsigned short*)alloc((size_t)MP_ * 128 * 2);
  unsigned short* hid_hi = (unsigned short*)alloc((size_t)MP_ * 512 * 2);
  unsigned short* hid_lo = (unsigned short*)alloc((size_t)MP_ * 512 * 2);
  // weights (transposed, split)
  unsigned short* wqkv_hi = (unsigned short*)alloc((size_t)L_ * 384 * 128 * 2);
  unsigned short* wqkv_lo = (unsigned short*)alloc((size_t)L_ * 384 * 128 * 2);
  unsigned short* wo_hi   = (unsigned short*)alloc((size_t)L_ * 128 * 128 * 2);
  unsigned short* wo_lo   = (unsigned short*)alloc((size_t)L_ * 128 * 128 * 2);
  unsigned short* w1_hi   = (unsigned short*)alloc((size_t)L_ * 512 * 128 * 2);
  unsigned short* w1_lo   = (unsigned short*)alloc((size_t)L_ * 512 * 128 * 2);
  unsigned short* w2_hi   = (unsigned short*)alloc((size_t)L_ * 128 * 512 * 2);
  unsigned short* w2_lo   = (unsigned short*)alloc((size_t)L_ * 128 * 512 * 2);
  unsigned short* we_hi   = (unsigned short*)alloc((size_t)128 * 64 * 2);
  unsigned short* we_lo   = (unsigned short*)alloc((size_t)128 * 64 * 2);
  float* qkvb = (float*)alloc((size_t)L_ * 384 * 4);
  float* gsum = (float*)alloc(128 * 4);
  int* deg  = (int*)alloc((size_t)N_ * 4);
  int* cur  = (int*)alloc((size_t)N_ * 4);
  int* offs = (int*)alloc(((size_t)N_ + 1) * 4);
  int* csrc = (int*)alloc((size_t)E_ * 4);
  // node-feature planes alias the hid planes (nf dead before hid is written)
  unsigned short* nf_hi = hid_hi;
  unsigned short* nf_lo = hid_lo;

  const int* esrc = ei;
  const int* edst = ei + E_;

  // ---- CSR build ----
  init_zero_k<<<64, 256, 0, stream>>>(deg, cur, gsum, N_);
  deg_k<<<(E_ + 255) / 256, 256, 0, stream>>>(edst, deg, E_);
  scan_k<<<1, 1024, 0, stream>>>(deg, offs, N_);
  fill_k<<<(E_ + 255) / 256, 256, 0, stream>>>(esrc, edst, offs, cur, csrc, E_);

  // ---- weight conversions ----
  auto wgrid = [](int total) { int g = (total + 255) / 256; return g > 2048 ? 2048 : g; };
  wsplit_k<<<wgrid(L_*128*128), 256, 0, stream>>>(qw, wqkv_hi, wqkv_lo, L_, 128, 128, 384*128, 0);
  wsplit_k<<<wgrid(L_*128*128), 256, 0, stream>>>(kw, wqkv_hi, wqkv_lo, L_, 128, 128, 384*128, 128);
  wsplit_k<<<wgrid(L_*128*128), 256, 0, stream>>>(vw, wqkv_hi, wqkv_lo, L_, 128, 128, 384*128, 256);
  wsplit_k<<<wgrid(L_*128*128), 256, 0, stream>>>(ow, wo_hi, wo_lo, L_, 128, 128, 128*128, 0);
  wsplit_k<<<wgrid(L_*128*512), 256, 0, stream>>>(mw1, w1_hi, w1_lo, L_, 128, 512, 512*128, 0);
  wsplit_k<<<wgrid(L_*512*128), 256, 0, stream>>>(mw2, w2_hi, w2_lo, L_, 512, 128, 128*512, 0);
  wsplit_k<<<wgrid(64*128), 256, 0, stream>>>(emb_w, we_hi, we_lo, 1, 64, 128, 128*64, 0);
  qkvbias_k<<<(L_*384 + 255) / 256, 256, 0, stream>>>(qb, kb, vb, qkvb);
  nfsplit_k<<<2048, 256, 0, stream>>>(node_features, nf_hi, nf_lo, N_ * 64);

  const int MB = (N_ + 63) / 64;  // 313

  // ---- embed: h = nf @ emb_w + emb_b (f32 + planes) ----
  mgemm_k<0, true, true><<<dim3(MB, 1), 256, 0, stream>>>(
      nf_hi, nf_lo, we_hi, we_lo, emb_b, nullptr, h, h_hi, h_lo, N_, 128, 64);

  for (int i = 0; i < L_; ++i) {
    const unsigned short* wq_h = wqkv_hi + (size_t)i * 384 * 128;
    const unsigned short* wq_l = wqkv_lo + (size_t)i * 384 * 128;

    // fused QKV: qkv[M][384] fp32
    mgemm_k<0, true, false><<<dim3(MB, 3), 256, 0, stream>>>(
        h_hi, h_lo, wq_h, wq_l, qkvb + (size_t)i * 384, nullptr,
        qkv, nullptr, nullptr, N_, 384, 128);

    // attention -> agg planes (sp)
    attn_k<<<(2 * N_ * 64 + 255) / 256, 256, 0, stream>>>(qkv, offs, csrc, sp_hi, sp_lo, N_);

    // O projection -> tmp fp32
    mgemm_k<0, true, false><<<dim3(MB, 1), 256, 0, stream>>>(
        sp_hi, sp_lo, wo_hi + (size_t)i * 128 * 128, wo_lo + (size_t)i * 128 * 128,
        ob + (size_t)i * 128, nullptr, tmp, nullptr, nullptr, N_, 128, 128);

    // LN(tmp + h) -> tmp (in-place f32) + sp planes
    ln_res_k<<<(N_ * 64 + 255) / 256, 256, 0, stream>>>(
        tmp, h, lnw + (size_t)i * 128, lnb + (size_t)i * 128, tmp, sp_hi, sp_lo, N_);

    // MLP up: hid planes = gelu(ln @ mw1 + mb1)
    mgemm_k<1, false, true><<<dim3(MB, 4), 256, 0, stream>>>(
        sp_hi, sp_lo, w1_hi + (size_t)i * 512 * 128, w1_lo + (size_t)i * 512 * 128,
        mb1 + (size_t)i * 512, nullptr, nullptr, hid_hi, hid_lo, N_, 512, 128);

    // MLP down + residual(ln f32): h = hid @ mw2 + mb2 + tmp  (f32 + planes)
    mgemm_k<2, true, true><<<dim3(MB, 1), 256, 0, stream>>>(
        hid_hi, hid_lo, w2_hi + (size_t)i * 128 * 512, w2_lo + (size_t)i * 128 * 512,
        mb2 + (size_t)i * 128, tmp, h, h_hi, h_lo, N_, 128, 512);
  }

  copy_k<<<2048, 256, 0, stream>>>(h, out_h, N_ * DIM_);
  colsum_k<<<64, 256, 0, stream>>>(h, gsum, N_);
  classifier_k<<<1, 256, 0, stream>>>(gsum, clnw, clnb, cw1, cb1, cw2, cb2, clsw, clsb,
                                      out, out_g, 1.0f / (float)N_);
}

// Round 3
// 1240.490 us; speedup vs baseline: 1.2030x; 1.0493x over previous
//
#include <hip/hip_runtime.h>
#include <hip/hip_bf16.h>
#include <cstdint>
#include <cstddef>

constexpr int N_  = 20000;
constexpr int E_  = 320000;
constexpr int DIM_ = 128;
constexpr int L_  = 4;
constexpr int MP_ = 20032;   // M padded to multiple of 64

typedef short bf16x8 __attribute__((ext_vector_type(8)));
typedef float f32x4  __attribute__((ext_vector_type(4)));

__device__ __forceinline__ float gelu_f(float x) {
  float x3 = x * x * x;
  float t = tanhf(0.7978845608028654f * (x + 0.044715f * x3));
  return 0.5f * x * (1.0f + t);
}

__device__ __forceinline__ unsigned short f2bf(float x) {  // RNE
  unsigned u = __float_as_uint(x);
  u += 0x7fff + ((u >> 16) & 1);
  return (unsigned short)(u >> 16);
}
__device__ __forceinline__ float bf2f(unsigned short s) {
  return __uint_as_float((unsigned)s << 16);
}
__device__ __forceinline__ void splitf(float x, unsigned short& h, unsigned short& l) {
  h = f2bf(x);
  l = f2bf(x - bf2f(h));
}

// ---------------------------------------------------------------------------
// MFMA GEMM, bf16x2 split (Ahi*Bhi + Ahi*Blo + Alo*Bhi ~= fp32).
// Compile-time K and NC: B offsets fold to immediates, k-loop unrolls.
// Block: 256 thr = 4 waves; block tile 64 rows x 64 cols; wave tile 16x64.
// A planes [M][K] bf16; Bt planes [NC][K] bf16 (pre-transposed).
// 16x16x32 frag: A/B row|col = lane&15, k0 = (lane>>4)*8.  C/D: col=lane&15,
// row=(lane>>4)*4+reg.  EPI: 0 none, 1 gelu, 2 +res.
// ---------------------------------------------------------------------------
template <int K, int NC, int EPI, bool WF32, bool WBF>
__global__ __launch_bounds__(256) void mgemm_k(
    const unsigned short* __restrict__ Ahi, const unsigned short* __restrict__ Alo,
    const unsigned short* __restrict__ Bthi, const unsigned short* __restrict__ Btlo,
    const float* __restrict__ bias, const float* __restrict__ res,
    float* __restrict__ Cf, unsigned short* __restrict__ Chi, unsigned short* __restrict__ Clo,
    int M)
{
  const int wave = threadIdx.x >> 6;
  const int lane = threadIdx.x & 63;
  const int l15  = lane & 15;
  const int kq8  = (lane >> 4) * 8;
  const int r0   = blockIdx.x * 64 + wave * 16;
  const int c0   = blockIdx.y * 64;

  f32x4 acc[4];
#pragma unroll
  for (int ct = 0; ct < 4; ++ct) acc[ct] = (f32x4){0.f, 0.f, 0.f, 0.f};

  const unsigned short* arh = Ahi + (size_t)(r0 + l15) * K + kq8;
  const unsigned short* arl = Alo + (size_t)(r0 + l15) * K + kq8;
  const unsigned short* bth = Bthi + (size_t)(c0 + l15) * K + kq8;
  const unsigned short* btl = Btlo + (size_t)(c0 + l15) * K + kq8;

#pragma unroll 4
  for (int k0 = 0; k0 < K; k0 += 32) {
    bf16x8 ah = *(const bf16x8*)(arh + k0);
    bf16x8 al = *(const bf16x8*)(arl + k0);
#pragma unroll
    for (int ct = 0; ct < 4; ++ct) {
      bf16x8 bh = *(const bf16x8*)(bth + ct * 16 * K + k0);
      bf16x8 bl = *(const bf16x8*)(btl + ct * 16 * K + k0);
      acc[ct] = __builtin_amdgcn_mfma_f32_16x16x32_bf16(ah, bh, acc[ct], 0, 0, 0);
      acc[ct] = __builtin_amdgcn_mfma_f32_16x16x32_bf16(ah, bl, acc[ct], 0, 0, 0);
      acc[ct] = __builtin_amdgcn_mfma_f32_16x16x32_bf16(al, bh, acc[ct], 0, 0, 0);
    }
  }

  const int ccol  = lane & 15;
  const int crow0 = (lane >> 4) * 4;
#pragma unroll
  for (int ct = 0; ct < 4; ++ct) {
    int gc = c0 + ct * 16 + ccol;
    float bb = bias[gc];
#pragma unroll
    for (int r = 0; r < 4; ++r) {
      int gr = r0 + crow0 + r;
      if (gr >= M) continue;
      float o = acc[ct][r] + bb;
      if (EPI == 1) o = gelu_f(o);
      if (EPI == 2) o += res[(size_t)gr * NC + gc];
      if (WF32) Cf[(size_t)gr * NC + gc] = o;
      if (WBF) {
        unsigned short hh, ll;
        splitf(o, hh, ll);
        Chi[(size_t)gr * NC + gc] = hh;
        Clo[(size_t)gr * NC + gc] = ll;
      }
    }
  }
}

// ---------------------------------------------------------------------------
// Weight transpose + split
// ---------------------------------------------------------------------------
__global__ __launch_bounds__(256) void wsplit_k(
    const float* __restrict__ in, unsigned short* __restrict__ hi,
    unsigned short* __restrict__ lo, int Lm, int K, int Nc,
    int layerStride, int rowOff)
{
  int total = Lm * K * Nc;
  for (int idx = blockIdx.x * blockDim.x + threadIdx.x; idx < total;
       idx += gridDim.x * blockDim.x) {
    int l = idx / (K * Nc);
    int r = idx - l * (K * Nc);
    int k = r / Nc;
    int c = r - k * Nc;
    float x = in[idx];
    size_t op = (size_t)l * layerStride + (size_t)(rowOff + c) * K + k;
    unsigned short hh, ll;
    splitf(x, hh, ll);
    hi[op] = hh; lo[op] = ll;
  }
}

__global__ __launch_bounds__(256) void qkvbias_k(
    const float* __restrict__ qb, const float* __restrict__ kb,
    const float* __restrict__ vb, float* __restrict__ out)
{
  int idx = blockIdx.x * blockDim.x + threadIdx.x;
  if (idx >= L_ * 384) return;
  int l = idx / 384, c = idx - l * 384;
  float x = (c < 128) ? qb[l * 128 + c] : (c < 256) ? kb[l * 128 + c - 128] : vb[l * 128 + c - 256];
  out[idx] = x;
}

__global__ __launch_bounds__(256) void nfsplit_k(
    const float* __restrict__ in, unsigned short* __restrict__ hi,
    unsigned short* __restrict__ lo, int total)
{
  for (int i = blockIdx.x * blockDim.x + threadIdx.x; i < total; i += gridDim.x * blockDim.x) {
    unsigned short hh, ll;
    splitf(in[i], hh, ll);
    hi[i] = hh; lo[i] = ll;
  }
}

// ---------------------------------------------------------------------------
// CSR build
// ---------------------------------------------------------------------------
__global__ __launch_bounds__(256) void init_zero_k(int* deg, int* cur, float* gsum, int n) {
  int i = blockIdx.x * blockDim.x + threadIdx.x;
  int st = gridDim.x * blockDim.x;
  for (int j = i; j < n; j += st) { deg[j] = 0; cur[j] = 0; }
  if (i < 128) gsum[i] = 0.f;
}

__global__ __launch_bounds__(256) void deg_k(const int* __restrict__ dst, int* __restrict__ deg, int E) {
  int e = blockIdx.x * blockDim.x + threadIdx.x;
  if (e < E) atomicAdd(&deg[dst[e]], 1);
}

__global__ __launch_bounds__(1024) void scan_k(const int* __restrict__ deg, int* __restrict__ offs, int n) {
  __shared__ int part[1024];
  int tid = threadIdx.x;
  const int chunk = (n + 1023) / 1024;
  int base = tid * chunk;
  int s = 0;
  for (int j = 0; j < chunk; ++j) { int idx = base + j; if (idx < n) s += deg[idx]; }
  part[tid] = s;
  __syncthreads();
  int own = s;
  for (int off = 1; off < 1024; off <<= 1) {
    int t = (tid >= off) ? part[tid - off] : 0;
    __syncthreads();
    part[tid] += t;
    __syncthreads();
  }
  int run = part[tid] - own;
  for (int j = 0; j < chunk; ++j) {
    int idx = base + j;
    if (idx <= n) offs[idx] = run;
    if (idx < n) run += deg[idx];
  }
}

__global__ __launch_bounds__(256) void fill_k(
    const int* __restrict__ src, const int* __restrict__ dst,
    const int* __restrict__ offs, int* __restrict__ cur,
    int* __restrict__ csrc, int E)
{
  int e = blockIdx.x * blockDim.x + threadIdx.x;
  if (e < E) {
    int d = dst[e];
    int p = atomicAdd(&cur[d], 1);
    csrc[offs[d] + p] = src[e];
  }
}

// ---------------------------------------------------------------------------
// Fused attention, online softmax with 4 independent chains (ILP) + merge.
// qkv [M][384]: q at col, k at 128+col, v at 256+col.
// One wave per (node, head-pair); 32-lane half-wave = one head.
// ---------------------------------------------------------------------------
__global__ __launch_bounds__(256) void attn_k(
    const float* __restrict__ qkv,
    const int* __restrict__ offs, const int* __restrict__ csrc,
    unsigned short* __restrict__ aggHi, unsigned short* __restrict__ aggLo, int M)
{
  int gw = (int)((blockIdx.x * blockDim.x + threadIdx.x) >> 6);
  int lane = threadIdx.x & 63;
  int n = gw >> 1, hp = gw & 1;
  if (n >= M) return;
  int col = hp * 64 + lane;
  float qv = qkv[(size_t)n * 384 + col] * 0.17677669529663687f;  // 1/sqrt(32)

  float m[4], den[4], acc[4];
#pragma unroll
  for (int j = 0; j < 4; ++j) { m[j] = -3.0e38f; den[j] = 0.f; acc[j] = 0.f; }

  const int e0 = offs[n], e1 = offs[n + 1];
  for (int base = e0; base < e1; base += 4) {
#pragma unroll
    for (int j = 0; j < 4; ++j) {
      int e = base + j;
      if (e < e1) {                       // wave-uniform branch
        int s = csrc[e];
        const float* row = qkv + (size_t)s * 384;
        float kv = row[128 + col];
        float vv = row[256 + col];
        float p = qv * kv;
        p += __shfl_xor(p, 1);
        p += __shfl_xor(p, 2);
        p += __shfl_xor(p, 4);
        p += __shfl_xor(p, 8);
        p += __shfl_xor(p, 16);
        float nm = fmaxf(m[j], p);
        float c = __expf(m[j] - nm);
        float w = __expf(p - nm);
        den[j] = den[j] * c + w;
        acc[j] = acc[j] * c + w * vv;
        m[j] = nm;
      }
    }
  }

  // merge 4 chains
  float M4 = fmaxf(fmaxf(m[0], m[1]), fmaxf(m[2], m[3]));
  float dsum = 0.f, asum = 0.f;
#pragma unroll
  for (int j = 0; j < 4; ++j) {
    float w = __expf(m[j] - M4);
    dsum += den[j] * w;
    asum += acc[j] * w;
  }
  float o = (e1 > e0) ? (asum / dsum) : 0.f;
  unsigned short hh, ll;
  splitf(o, hh, ll);
  aggHi[(size_t)n * 128 + col] = hh;
  aggLo[(size_t)n * 128 + col] = ll;
}

// ---------------------------------------------------------------------------
// LayerNorm(x + res): fp32 out (may alias x) + hi/lo planes
// ---------------------------------------------------------------------------
__global__ __launch_bounds__(256) void ln_res_k(
    const float* x, const float* __restrict__ res,
    const float* __restrict__ w, const float* __restrict__ b,
    float* outF, unsigned short* __restrict__ outHi, unsigned short* __restrict__ outLo, int M)
{
  int row = (int)((blockIdx.x * blockDim.x + threadIdx.x) >> 6);
  int lane = threadIdx.x & 63;
  if (row >= M) return;
  const float* xr = x + (size_t)row * 128;
  const float* rr = res + (size_t)row * 128;
  float v0 = xr[lane] + rr[lane];
  float v1 = xr[lane + 64] + rr[lane + 64];
  float s = v0 + v1;
#pragma unroll
  for (int d = 1; d < 64; d <<= 1) s += __shfl_xor(s, d);
  float mean = s * (1.f / 128.f);
  float e0 = v0 - mean, e1 = v1 - mean;
  float qs = e0 * e0 + e1 * e1;
#pragma unroll
  for (int d = 1; d < 64; d <<= 1) qs += __shfl_xor(qs, d);
  float rstd = rsqrtf(qs * (1.f / 128.f) + 1e-5f);
  float o0 = e0 * rstd * w[lane] + b[lane];
  float o1 = e1 * rstd * w[lane + 64] + b[lane + 64];
  outF[(size_t)row * 128 + lane] = o0;
  outF[(size_t)row * 128 + lane + 64] = o1;
  unsigned short hh, ll;
  splitf(o0, hh, ll);
  outHi[(size_t)row * 128 + lane] = hh; outLo[(size_t)row * 128 + lane] = ll;
  splitf(o1, hh, ll);
  outHi[(size_t)row * 128 + lane + 64] = hh; outLo[(size_t)row * 128 + lane + 64] = ll;
}

// ---------------------------------------------------------------------------
__global__ __launch_bounds__(256) void colsum_k(const float* __restrict__ h, float* __restrict__ gsum, int M) {
  __shared__ float sd[256];
  int tid = threadIdx.x;
  int d = tid & 127, half = tid >> 7;
  float s = 0.f;
  for (int r = blockIdx.x * 2 + half; r < M; r += gridDim.x * 2)
    s += h[(size_t)r * 128 + d];
  sd[tid] = s;
  __syncthreads();
  if (tid < 128) atomicAdd(&gsum[d], sd[tid] + sd[tid + 128]);
}

__global__ __launch_bounds__(256) void classifier_k(
    const float* __restrict__ gsum,
    const float* __restrict__ lnw, const float* __restrict__ lnb,
    const float* __restrict__ cw1, const float* __restrict__ cb1,
    const float* __restrict__ cw2, const float* __restrict__ cb2,
    const float* __restrict__ clsw, const float* __restrict__ clsb,
    float* __restrict__ out_logits, float* __restrict__ out_g, float invN)
{
  __shared__ float z[128], h1[256], z2[128];
  int tid = threadIdx.x;
  if (tid < 128) {
    float gg = gsum[tid] * invN;
    out_g[tid] = gg;
    z[tid] = gg;
  }
  __syncthreads();
  if (tid < 64) {
    float a = z[tid], b2 = z[tid + 64];
    float s = a + b2;
#pragma unroll
    for (int d = 1; d < 64; d <<= 1) s += __shfl_xor(s, d);
    float mean = s * (1.f / 128.f);
    float ea = a - mean, eb = b2 - mean;
    float sq = ea * ea + eb * eb;
#pragma unroll
    for (int d = 1; d < 64; d <<= 1) sq += __shfl_xor(sq, d);
    float rstd = rsqrtf(sq * (1.f / 128.f) + 1e-5f);
    z[tid]      = ea * rstd * lnw[tid] + lnb[tid];
    z[tid + 64] = eb * rstd * lnw[tid + 64] + lnb[tid + 64];
  }
  __syncthreads();
  {
    float acc = cb1[tid];
    for (int f = 0; f < 128; ++f) acc = fmaf(z[f], cw1[f * 256 + tid], acc);
    h1[tid] = gelu_f(acc);
  }
  __syncthreads();
  if (tid < 128) {
    float acc = cb2[tid];
    for (int f = 0; f < 256; ++f) acc = fmaf(h1[f], cw2[f * 128 + tid], acc);
    z2[tid] = acc;
  }
  __syncthreads();
  if (tid < 10) {
    float acc = clsb[tid];
    for (int f = 0; f < 128; ++f) acc = fmaf(z2[f], clsw[f * 10 + tid], acc);
    out_logits[tid] = acc;
  }
}

// ---------------------------------------------------------------------------
extern "C" void kernel_launch(void* const* d_in, const int* in_sizes, int n_in,
                              void* d_out, int out_size, void* d_ws, size_t ws_size,
                              hipStream_t stream) {
  const float* node_features = (const float*)d_in[0];
  const int*   ei            = (const int*)d_in[1];
  const float* emb_w = (const float*)d_in[3];
  const float* emb_b = (const float*)d_in[4];
  const float* qw  = (const float*)d_in[7];  const float* qb  = (const float*)d_in[8];
  const float* kw  = (const float*)d_in[9];  const float* kb  = (const float*)d_in[10];
  const float* vw  = (const float*)d_in[11]; const float* vb  = (const float*)d_in[12];
  const float* ow  = (const float*)d_in[13]; const float* ob  = (const float*)d_in[14];
  const float* lnw = (const float*)d_in[15]; const float* lnb = (const float*)d_in[16];
  const float* mw1 = (const float*)d_in[17]; const float* mb1 = (const float*)d_in[18];
  const float* mw2 = (const float*)d_in[19]; const float* mb2 = (const float*)d_in[20];
  const float* clnw = (const float*)d_in[21]; const float* clnb = (const float*)d_in[22];
  const float* cw1 = (const float*)d_in[23]; const float* cb1 = (const float*)d_in[24];
  const float* cw2 = (const float*)d_in[25]; const float* cb2 = (const float*)d_in[26];
  const float* clsw = (const float*)d_in[27]; const float* clsb = (const float*)d_in[28];

  float* out = (float*)d_out;
  float* out_h = out + 10;
  float* out_g = out + 10 + (size_t)N_ * DIM_;

  char* p = (char*)d_ws;
  auto alloc = [&](size_t bytes) { char* r = p; p += (bytes + 255) & ~(size_t)255; return r; };

  float* h    = (float*)alloc((size_t)MP_ * 128 * 4);
  float* qkv  = (float*)alloc((size_t)MP_ * 384 * 4);
  float* tmp  = (float*)alloc((size_t)MP_ * 128 * 4);
  unsigned short* h_hi = (unsigned short*)alloc((size_t)MP_ * 128 * 2);
  unsigned short* h_lo = (unsigned short*)alloc((size_t)MP_ * 128 * 2);
  unsigned short* sp_hi = (unsigned short*)alloc((size_t)MP_ * 128 * 2);
  unsigned short* sp_lo = (unsigned short*)alloc((size_t)MP_ * 128 * 2);
  unsigned short* hid_hi = (unsigned short*)alloc((size_t)MP_ * 512 * 2);
  unsigned short* hid_lo = (unsigned short*)alloc((size_t)MP_ * 512 * 2);
  unsigned short* wqkv_hi = (unsigned short*)alloc((size_t)L_ * 384 * 128 * 2);
  unsigned short* wqkv_lo = (unsigned short*)alloc((size_t)L_ * 384 * 128 * 2);
  unsigned short* wo_hi   = (unsigned short*)alloc((size_t)L_ * 128 * 128 * 2);
  unsigned short* wo_lo   = (unsigned short*)alloc((size_t)L_ * 128 * 128 * 2);
  unsigned short* w1_hi   = (unsigned short*)alloc((size_t)L_ * 512 * 128 * 2);
  unsigned short* w1_lo   = (unsigned short*)alloc((size_t)L_ * 512 * 128 * 2);
  unsigned short* w2_hi   = (unsigned short*)alloc((size_t)L_ * 128 * 512 * 2);
  unsigned short* w2_lo   = (unsigned short*)alloc((size_t)L_ * 128 * 512 * 2);
  unsigned short* we_hi   = (unsigned short*)alloc((size_t)128 * 64 * 2);
  unsigned short* we_lo   = (unsigned short*)alloc((size_t)128 * 64 * 2);
  float* qkvb = (float*)alloc((size_t)L_ * 384 * 4);
  float* gsum = (float*)alloc(128 * 4);
  int* deg  = (int*)alloc((size_t)N_ * 4);
  int* cur  = (int*)alloc((size_t)N_ * 4);
  int* offs = (int*)alloc(((size_t)N_ + 1) * 4);
  int* csrc = (int*)alloc((size_t)E_ * 4);
  unsigned short* nf_hi = hid_hi;   // alias: nf planes dead before hid written
  unsigned short* nf_lo = hid_lo;

  const int* esrc = ei;
  const int* edst = ei + E_;

  // CSR build
  init_zero_k<<<64, 256, 0, stream>>>(deg, cur, gsum, N_);
  deg_k<<<(E_ + 255) / 256, 256, 0, stream>>>(edst, deg, E_);
  scan_k<<<1, 1024, 0, stream>>>(deg, offs, N_);
  fill_k<<<(E_ + 255) / 256, 256, 0, stream>>>(esrc, edst, offs, cur, csrc, E_);

  // weight conversions
  auto wgrid = [](int total) { int g = (total + 255) / 256; return g > 2048 ? 2048 : g; };
  wsplit_k<<<wgrid(L_*128*128), 256, 0, stream>>>(qw, wqkv_hi, wqkv_lo, L_, 128, 128, 384*128, 0);
  wsplit_k<<<wgrid(L_*128*128), 256, 0, stream>>>(kw, wqkv_hi, wqkv_lo, L_, 128, 128, 384*128, 128);
  wsplit_k<<<wgrid(L_*128*128), 256, 0, stream>>>(vw, wqkv_hi, wqkv_lo, L_, 128, 128, 384*128, 256);
  wsplit_k<<<wgrid(L_*128*128), 256, 0, stream>>>(ow, wo_hi, wo_lo, L_, 128, 128, 128*128, 0);
  wsplit_k<<<wgrid(L_*128*512), 256, 0, stream>>>(mw1, w1_hi, w1_lo, L_, 128, 512, 512*128, 0);
  wsplit_k<<<wgrid(L_*512*128), 256, 0, stream>>>(mw2, w2_hi, w2_lo, L_, 512, 128, 128*512, 0);
  wsplit_k<<<wgrid(64*128), 256, 0, stream>>>(emb_w, we_hi, we_lo, 1, 64, 128, 128*64, 0);
  qkvbias_k<<<(L_*384 + 255) / 256, 256, 0, stream>>>(qb, kb, vb, qkvb);
  nfsplit_k<<<2048, 256, 0, stream>>>(node_features, nf_hi, nf_lo, N_ * 64);

  const int MB = (N_ + 63) / 64;  // 313

  // embed: h = nf @ emb_w + emb_b
  mgemm_k<64, 128, 0, true, true><<<dim3(MB, 2), 256, 0, stream>>>(
      nf_hi, nf_lo, we_hi, we_lo, emb_b, nullptr, h, h_hi, h_lo, N_);

  for (int i = 0; i < L_; ++i) {
    const unsigned short* wq_h = wqkv_hi + (size_t)i * 384 * 128;
    const unsigned short* wq_l = wqkv_lo + (size_t)i * 384 * 128;

    // fused QKV -> qkv[M][384] fp32
    mgemm_k<128, 384, 0, true, false><<<dim3(MB, 6), 256, 0, stream>>>(
        h_hi, h_lo, wq_h, wq_l, qkvb + (size_t)i * 384, nullptr,
        qkv, nullptr, nullptr, N_);

    // attention -> agg planes (sp)
    attn_k<<<(2 * N_ * 64 + 255) / 256, 256, 0, stream>>>(qkv, offs, csrc, sp_hi, sp_lo, N_);

    // O projection -> tmp fp32
    mgemm_k<128, 128, 0, true, false><<<dim3(MB, 2), 256, 0, stream>>>(
        sp_hi, sp_lo, wo_hi + (size_t)i * 128 * 128, wo_lo + (size_t)i * 128 * 128,
        ob + (size_t)i * 128, nullptr, tmp, nullptr, nullptr, N_);

    // LN(tmp + h) -> tmp (in-place) + sp planes
    ln_res_k<<<(N_ * 64 + 255) / 256, 256, 0, stream>>>(
        tmp, h, lnw + (size_t)i * 128, lnb + (size_t)i * 128, tmp, sp_hi, sp_lo, N_);

    // MLP up: hid planes = gelu(ln @ mw1 + mb1)
    mgemm_k<128, 512, 1, false, true><<<dim3(MB, 8), 256, 0, stream>>>(
        sp_hi, sp_lo, w1_hi + (size_t)i * 512 * 128, w1_lo + (size_t)i * 512 * 128,
        mb1 + (size_t)i * 512, nullptr, nullptr, hid_hi, hid_lo, N_);

    // MLP down + residual: h = hid @ mw2 + mb2 + tmp  (last layer writes out_h)
    float* hdst = (i == L_ - 1) ? out_h : h;
    mgemm_k<512, 128, 2, true, true><<<dim3(MB, 2), 256, 0, stream>>>(
        hid_hi, hid_lo, w2_hi + (size_t)i * 128 * 512, w2_lo + (size_t)i * 128 * 512,
        mb2 + (size_t)i * 128, tmp, hdst, h_hi, h_lo, N_);
  }

  colsum_k<<<64, 256, 0, stream>>>(out_h, gsum, N_);
  classifier_k<<<1, 256, 0, stream>>>(gsum, clnw, clnb, cw1, cb1, cw2, cb2, clsw, clsb,
                                      out, out_g, 1.0f / (float)N_);
}